// Round 4
// baseline (439.264 us; speedup 1.0000x reference)
//
#include <hip/hip_runtime.h>

#define HW 1024
#define CD 512

typedef __bf16 bf16x8 __attribute__((ext_vector_type(8)));
typedef float f32x4 __attribute__((ext_vector_type(4)));

__device__ __forceinline__ unsigned short f2bf(float f) {
    unsigned int u = __float_as_uint(f);
    u += 0x7fff + ((u >> 16) & 1);   // RNE
    return (unsigned short)(u >> 16);
}

#define AS1(p) ((__attribute__((address_space(1))) void*)(p))
#define AS3(p) ((__attribute__((address_space(3))) void*)(p))
#define GLD16(gp, lp) __builtin_amdgcn_global_load_lds(AS1(gp), AS3(lp), 16, 0, 0)

// ---------------- GroupNorm stats: one block per (b,g); group = 65536 contiguous f32
__global__ __launch_bounds__(256)
void gn_stats(const float* __restrict__ x, float* __restrict__ mean, float* __restrict__ rstd) {
    int bg = blockIdx.x;
    const float4* p4 = (const float4*)(x + (size_t)bg * 65536);
    int tid = threadIdx.x;
    float s = 0.f, ss = 0.f;
#pragma unroll 8
    for (int it = 0; it < 64; ++it) {
        float4 v = p4[tid + it * 256];
        s  += v.x + v.y + v.z + v.w;
        ss += v.x * v.x + v.y * v.y + v.z * v.z + v.w * v.w;
    }
#pragma unroll
    for (int d = 32; d > 0; d >>= 1) { s += __shfl_down(s, d); ss += __shfl_down(ss, d); }
    __shared__ float ls[4], lss[4];
    if ((tid & 63) == 0) { ls[tid >> 6] = s; lss[tid >> 6] = ss; }
    __syncthreads();
    if (tid == 0) {
        float S = ls[0] + ls[1] + ls[2] + ls[3];
        float SS = lss[0] + lss[1] + lss[2] + lss[3];
        float m = S * (1.f / 65536.f);
        float v = SS * (1.f / 65536.f) - m * m;
        mean[bg] = m;
        rstd[bg] = rsqrtf(v + 1e-5f);
    }
}

// ---------------- normalize + transpose: x[b,c,hw] f32 -> xnT[b,hw,c] bf16
__global__ __launch_bounds__(256)
void gn_norm_t(const float* __restrict__ x, const float* __restrict__ mean, const float* __restrict__ rstd,
               const float* __restrict__ gamma, const float* __restrict__ beta,
               unsigned short* __restrict__ xnT) {
    __shared__ unsigned short tile[64][72];
    int i0 = blockIdx.x * 64, c0 = blockIdx.y * 64, b = blockIdx.z;
    float m = mean[b * 8 + blockIdx.y];
    float r = rstd[b * 8 + blockIdx.y];
    int tid = threadIdx.x;
    int tr = tid >> 4, tc = (tid & 15) * 4;
    const float* xb = x + ((size_t)b * CD + c0) * HW + i0;
#pragma unroll
    for (int p = 0; p < 4; ++p) {
        int c = tr + p * 16;
        float g = gamma[c0 + c] * r;
        float bb = beta[c0 + c] - m * g;
        float4 v = *(const float4*)(xb + (size_t)c * HW + tc);
        tile[c][tc + 0] = f2bf(v.x * g + bb);
        tile[c][tc + 1] = f2bf(v.y * g + bb);
        tile[c][tc + 2] = f2bf(v.z * g + bb);
        tile[c][tc + 3] = f2bf(v.w * g + bb);
    }
    __syncthreads();
    unsigned short* ob = xnT + ((size_t)b * HW + i0) * CD + c0;
#pragma unroll
    for (int p = 0; p < 4; ++p) {
        int ir = tr + p * 16;
        ushort4 u;
        u.x = tile[tc + 0][ir];
        u.y = tile[tc + 1][ir];
        u.z = tile[tc + 2][ir];
        u.w = tile[tc + 3][ir];
        *(ushort4*)(ob + (size_t)ir * CD + tc) = u;
    }
}

// ---------------- f32 -> bf16 weight convert (qkv_w rows 0..1023)
__global__ __launch_bounds__(256)
void cvt_bf16(const float* __restrict__ src, unsigned short* __restrict__ dst) {
    int i = blockIdx.x * 256 + threadIdx.x;
    float4 v = ((const float4*)src)[i];
    ushort4 u;
    u.x = f2bf(v.x); u.y = f2bf(v.y); u.z = f2bf(v.z); u.w = f2bf(v.w);
    ((ushort4*)dst)[i] = u;
}

// ---------------- W2 = out_w @ w_v (f32 math, bf16 store); bias2 = out_w @ b_v
__global__ __launch_bounds__(256)
void w2_kernel(const float* __restrict__ out_w, const float* __restrict__ qkv_w,
               const float* __restrict__ qkv_b, unsigned short* __restrict__ w2,
               float* __restrict__ bias2) {
    int bo = blockIdx.x;          // 64 blocks x 8 rows
    int tid = threadIdx.x;        // 256 threads x 2 cols
    int c2 = tid * 2;
    const float* wv = qkv_w + (size_t)1024 * CD;
    const float* bv = qkv_b + 1024;
    float acc0[8] = {}, acc1[8] = {}, b2[8] = {};
    for (int t = 0; t < CD; ++t) {
        float2 v = *(const float2*)(wv + (size_t)t * CD + c2);
        float bvt = bv[t];
#pragma unroll
        for (int r = 0; r < 8; ++r) {
            float ow = out_w[(size_t)(bo * 8 + r) * CD + t];
            acc0[r] += ow * v.x;
            acc1[r] += ow * v.y;
            b2[r]   += ow * bvt;
        }
    }
#pragma unroll
    for (int r = 0; r < 8; ++r) {
        unsigned int pack = (unsigned int)f2bf(acc0[r]) | ((unsigned int)f2bf(acc1[r]) << 16);
        *(unsigned int*)(w2 + (size_t)(bo * 8 + r) * CD + c2) = pack;
        if (tid == 0) bias2[bo * 8 + r] = b2[r];
    }
}

// ---------------- generic bf16 GEMM, C[M,N] = A[M,K] * B[N,K]^T
// EPI 0: bf16 out + bias[col]   (qk^T)
// EPI 1: bf16 out + bias[row]   (vproj)
// EPI 2: f32 out + bias[row] + residual   (final)
template<int EPI>
__global__ __launch_bounds__(256, 2)
void gemm_bt(const unsigned short* __restrict__ A, const unsigned short* __restrict__ B,
             void* __restrict__ Cv, const float* __restrict__ bias,
             const float* __restrict__ resid,
             int M, int N, int K, long long sA, long long sB, long long sC, long long sR) {
    // bijective XCD swizzle (grid always divisible by 8)
    unsigned nx = gridDim.x, ny = gridDim.y;
    unsigned lin = blockIdx.x + nx * (blockIdx.y + ny * blockIdx.z);
    unsigned nwg = nx * ny * gridDim.z;
    unsigned work = (lin & 7) * (nwg >> 3) + (lin >> 3);
    unsigned bx = work % nx; work /= nx;
    unsigned by = work % ny;
    unsigned bz = work / ny;

    A += (size_t)bz * sA;
    B += (size_t)bz * sB;
    int m0 = by * 128, n0 = bx * 128;

    __shared__ unsigned short lA[128 * 64];
    __shared__ unsigned short lB[128 * 64];

    int tid = threadIdx.x;
    int lane = tid & 63;
    int wr = (tid >> 6) >> 1, wc = (tid >> 6) & 1;   // 2x2 waves, 64x64 each

    f32x4 acc[4][4] = {};

    int strow[4], stcol[4];
#pragma unroll
    for (int s = 0; s < 4; ++s) {
        int row = (s * 256 + tid) >> 3;
        int g = (tid & 7) ^ (row & 7);
        strow[s] = row;
        stcol[s] = g * 8;
    }

    for (int k0 = 0; k0 < K; k0 += 64) {
#pragma unroll
        for (int s = 0; s < 4; ++s) {
            GLD16(A + (size_t)(m0 + strow[s]) * K + k0 + stcol[s], lA + (size_t)(s * 256 + tid) * 8);
            GLD16(B + (size_t)(n0 + strow[s]) * K + k0 + stcol[s], lB + (size_t)(s * 256 + tid) * 8);
        }
        __syncthreads();
#pragma unroll
        for (int kk = 0; kk < 64; kk += 32) {
            bf16x8 af[4], bfr[4];
#pragma unroll
            for (int m = 0; m < 4; ++m) {
                int row = wr * 64 + m * 16 + (lane & 15);
                int off = (row * 128 + (kk + (lane >> 4) * 8) * 2) ^ ((row & 7) << 4);
                af[m] = *(const bf16x8*)((const char*)lA + off);
            }
#pragma unroll
            for (int n = 0; n < 4; ++n) {
                int row = wc * 64 + n * 16 + (lane & 15);
                int off = (row * 128 + (kk + (lane >> 4) * 8) * 2) ^ ((row & 7) << 4);
                bfr[n] = *(const bf16x8*)((const char*)lB + off);
            }
#pragma unroll
            for (int m = 0; m < 4; ++m)
#pragma unroll
                for (int n = 0; n < 4; ++n)
                    acc[m][n] = __builtin_amdgcn_mfma_f32_16x16x32_bf16(af[m], bfr[n], acc[m][n], 0, 0, 0);
        }
        __syncthreads();
    }

    int rl = (lane >> 4) * 4;
    int cl = lane & 15;
    if (EPI == 2) {
        float* Cf = (float*)Cv + (size_t)bz * sC;
        const float* Rs = resid + (size_t)bz * sR;
#pragma unroll
        for (int m = 0; m < 4; ++m)
#pragma unroll
            for (int n = 0; n < 4; ++n) {
                int gm = m0 + wr * 64 + m * 16 + rl;
                int gn = n0 + wc * 64 + n * 16 + cl;
#pragma unroll
                for (int rg = 0; rg < 4; ++rg) {
                    size_t off = (size_t)(gm + rg) * N + gn;
                    Cf[off] = acc[m][n][rg] + bias[gm + rg] + Rs[off];
                }
            }
    } else {
        unsigned short* Cb = (unsigned short*)Cv + (size_t)bz * sC;
#pragma unroll
        for (int m = 0; m < 4; ++m)
#pragma unroll
            for (int n = 0; n < 4; ++n) {
                int gm = m0 + wr * 64 + m * 16 + rl;
                int gn = n0 + wc * 64 + n * 16 + cl;
#pragma unroll
                for (int rg = 0; rg < 4; ++rg) {
                    float v = acc[m][n][rg] + (EPI == 0 ? bias[gn] : bias[gm + rg]);
                    Cb[(size_t)(gm + rg) * N + gn] = f2bf(v);
                }
            }
    }
}

// ---------------- fused scores + row softmax v3: no LDS staging, k read from L2.
// qk layout: [b][i][o], o in [0,512)=q^T, [512,1024)=k^T.
// Block: 256 threads (4 waves), 16 q-rows, full 1024 cols.
// Wave w owns cols jt*128 + w*32 .. +32 for each of 8 j-tiles; q in registers.
// Zero barriers in the main loop (k is L2-resident; latency hidden by ILP).
__global__ __launch_bounds__(256, 2)
void attn_softmax(const unsigned short* __restrict__ qk, unsigned short* __restrict__ P) {
    // XCD swizzle: 2048 blocks -> 256/XCD
    unsigned bid = blockIdx.x;
    unsigned work = (bid & 7) * 256 + (bid >> 3);
    int b = work >> 6;
    int i0 = (work & 63) * 16;
    const unsigned short* qkb = qk + (size_t)b * HW * HW;

    __shared__ float red[4][16];

    int tid = threadIdx.x, lane = tid & 63, wid = tid >> 6;

    // ---- q fragments in registers: rows i0..i0+15, all K=512
    bf16x8 af[16];
    {
        const unsigned short* qrow = qkb + (size_t)(i0 + (lane & 15)) * HW + (lane >> 4) * 8;
#pragma unroll
        for (int k = 0; k < 16; ++k)
            af[k] = *(const bf16x8*)(qrow + k * 32);
    }

    f32x4 acc[8][2] = {};

#pragma unroll
    for (int jt = 0; jt < 8; ++jt) {
        // k^T rows (= score cols) for this wave's 32-col slice
        const unsigned short* kb0 = qkb + (size_t)(jt * 128 + wid * 32 + (lane & 15)) * HW + 512 + (lane >> 4) * 8;
        const unsigned short* kb1 = kb0 + 16 * HW;
#pragma unroll
        for (int kc = 0; kc < 16; ++kc) {
            bf16x8 b0 = *(const bf16x8*)(kb0 + kc * 32);
            bf16x8 b1 = *(const bf16x8*)(kb1 + kc * 32);
            acc[jt][0] = __builtin_amdgcn_mfma_f32_16x16x32_bf16(af[kc], b0, acc[jt][0], 0, 0, 0);
            acc[jt][1] = __builtin_amdgcn_mfma_f32_16x16x32_bf16(af[kc], b1, acc[jt][1], 0, 0, 0);
        }
    }

    // ---- softmax over full rows (exp(scale*(S-max)) via exp2)
    const float SL2E = 0.044194173824159216f * 1.4426950408889634f;
    int rowl = (lane >> 4) * 4;
    float rmax[4], rsum[4];
#pragma unroll
    for (int r = 0; r < 4; ++r) { rmax[r] = -1e30f; rsum[r] = 0.f; }

#pragma unroll
    for (int jt = 0; jt < 8; ++jt)
#pragma unroll
        for (int n = 0; n < 2; ++n)
#pragma unroll
            for (int r = 0; r < 4; ++r) rmax[r] = fmaxf(rmax[r], acc[jt][n][r]);
#pragma unroll
    for (int d = 1; d < 16; d <<= 1)
#pragma unroll
        for (int r = 0; r < 4; ++r) rmax[r] = fmaxf(rmax[r], __shfl_xor(rmax[r], d));
    if ((lane & 15) == 0)
#pragma unroll
        for (int r = 0; r < 4; ++r) red[wid][rowl + r] = rmax[r];
    __syncthreads();
#pragma unroll
    for (int r = 0; r < 4; ++r)
        rmax[r] = fmaxf(fmaxf(red[0][rowl + r], red[1][rowl + r]),
                        fmaxf(red[2][rowl + r], red[3][rowl + r]));
    __syncthreads();

#pragma unroll
    for (int jt = 0; jt < 8; ++jt)
#pragma unroll
        for (int n = 0; n < 2; ++n)
#pragma unroll
            for (int r = 0; r < 4; ++r) {
                float e = __builtin_amdgcn_exp2f((acc[jt][n][r] - rmax[r]) * SL2E);
                acc[jt][n][r] = e;
                rsum[r] += e;
            }
#pragma unroll
    for (int d = 1; d < 16; d <<= 1)
#pragma unroll
        for (int r = 0; r < 4; ++r) rsum[r] += __shfl_xor(rsum[r], d);
    if ((lane & 15) == 0)
#pragma unroll
        for (int r = 0; r < 4; ++r) red[wid][rowl + r] = rsum[r];
    __syncthreads();
#pragma unroll
    for (int r = 0; r < 4; ++r)
        rsum[r] = 1.0f / (red[0][rowl + r] + red[1][rowl + r] + red[2][rowl + r] + red[3][rowl + r]);

    unsigned short* Pb = P + (size_t)b * HW * HW;
#pragma unroll
    for (int jt = 0; jt < 8; ++jt)
#pragma unroll
        for (int n = 0; n < 2; ++n)
#pragma unroll
            for (int r = 0; r < 4; ++r) {
                int row = i0 + rowl + r;
                int col = jt * 128 + wid * 32 + n * 16 + (lane & 15);
                Pb[(size_t)row * HW + col] = f2bf(acc[jt][n][r] * rsum[r]);
            }
}

// ---------------- launch
extern "C" void kernel_launch(void* const* d_in, const int* in_sizes, int n_in,
                              void* d_out, int out_size, void* d_ws, size_t ws_size,
                              hipStream_t stream) {
    const float* x      = (const float*)d_in[0];
    const float* gamma  = (const float*)d_in[1];
    const float* beta   = (const float*)d_in[2];
    const float* qkv_w  = (const float*)d_in[3];
    const float* qkv_b  = (const float*)d_in[4];
    const float* out_w  = (const float*)d_in[5];
    const float* out_b  = (const float*)d_in[6];

    char* ws = (char*)d_ws;
    unsigned short* xnT  = (unsigned short*)ws;                   // 32 MB, dead before P written
    unsigned short* P    = (unsigned short*)ws;                   // 64 MB (aliases xnT, written later)
    unsigned short* vpr  = (unsigned short*)(ws + 67108864);      // 32 MB
    unsigned short* wqk  = (unsigned short*)(ws + 100663296);     // 1 MB
    unsigned short* w2   = (unsigned short*)(ws + 101711872);     // 512 KB
    float* bias2         = (float*)(ws + 102236160);
    float* meanp         = (float*)(ws + 102238208);
    float* rstdp         = (float*)(ws + 102239232);

    unsigned short* qkT = (unsigned short*)d_out;   // 64 MB scratch, overwritten by final GEMM
    float* outF = (float*)d_out;

    gn_stats<<<256, 256, 0, stream>>>(x, meanp, rstdp);
    gn_norm_t<<<dim3(16, 8, 32), 256, 0, stream>>>(x, meanp, rstdp, gamma, beta, xnT);
    cvt_bf16<<<512, 256, 0, stream>>>(qkv_w, wqk);
    w2_kernel<<<64, 256, 0, stream>>>(out_w, qkv_w, qkv_b, w2, bias2);

    // qk^T[b,i,o] = xnT[b,i,:] . qkv_w[o,:]  + qkv_b[o]
    gemm_bt<0><<<dim3(8, 8, 32), 256, 0, stream>>>(xnT, wqk, qkT, qkv_b, nullptr,
        1024, 1024, 512, 1024LL * 512, 0, 1024LL * 1024, 0);
    // vproj[b,o,i] = W2[o,:] . xnT[b,i,:] + bias2[o]
    gemm_bt<1><<<dim3(8, 4, 32), 256, 0, stream>>>(w2, xnT, vpr, bias2, nullptr,
        512, 1024, 512, 0, 1024LL * 512, 512LL * 1024, 0);
    // P = softmax(q^T k * scale)
    attn_softmax<<<2048, 256, 0, stream>>>(qkT, P);
    // out[b,o,i] = vproj[b,o,:] . P[b,i,:] + out_b[o] + x[b,o,i]
    gemm_bt<2><<<dim3(8, 4, 32), 256, 0, stream>>>(vpr, P, outF, out_b, x,
        512, 1024, 1024, 512LL * 1024, 1024LL * 1024, 512LL * 1024, 512LL * 1024);
    (void)in_sizes; (void)n_in; (void)out_size; (void)ws_size;
}

// Round 5
// 247.909 us; speedup vs baseline: 1.7719x; 1.7719x over previous
//
#include <hip/hip_runtime.h>

#define HW 1024
#define CD 512

typedef __bf16 bf16x8 __attribute__((ext_vector_type(8)));
typedef float f32x4 __attribute__((ext_vector_type(4)));

__device__ __forceinline__ unsigned short f2bf(float f) {
    unsigned int u = __float_as_uint(f);
    u += 0x7fff + ((u >> 16) & 1);   // RNE
    return (unsigned short)(u >> 16);
}
__device__ __forceinline__ float bf2f(unsigned short h) {
    return __uint_as_float((unsigned)h << 16);
}

#define AS1(p) ((__attribute__((address_space(1))) void*)(p))
#define AS3(p) ((__attribute__((address_space(3))) void*)(p))
#define GLD16(gp, lp) __builtin_amdgcn_global_load_lds(AS1(gp), AS3(lp), 16, 0, 0)

// ---------------- GroupNorm stats: one block per (b,g); group = 65536 contiguous f32
__global__ __launch_bounds__(256)
void gn_stats(const float* __restrict__ x, float* __restrict__ mean, float* __restrict__ rstd) {
    int bg = blockIdx.x;
    const float4* p4 = (const float4*)(x + (size_t)bg * 65536);
    int tid = threadIdx.x;
    float s = 0.f, ss = 0.f;
#pragma unroll 8
    for (int it = 0; it < 64; ++it) {
        float4 v = p4[tid + it * 256];
        s  += v.x + v.y + v.z + v.w;
        ss += v.x * v.x + v.y * v.y + v.z * v.z + v.w * v.w;
    }
#pragma unroll
    for (int d = 32; d > 0; d >>= 1) { s += __shfl_down(s, d); ss += __shfl_down(ss, d); }
    __shared__ float ls[4], lss[4];
    if ((tid & 63) == 0) { ls[tid >> 6] = s; lss[tid >> 6] = ss; }
    __syncthreads();
    if (tid == 0) {
        float S = ls[0] + ls[1] + ls[2] + ls[3];
        float SS = lss[0] + lss[1] + lss[2] + lss[3];
        float m = S * (1.f / 65536.f);
        float v = SS * (1.f / 65536.f) - m * m;
        mean[bg] = m;
        rstd[bg] = rsqrtf(v + 1e-5f);
    }
}

// ---------------- normalize + transpose: x[b,c,hw] f32 -> xnT[b,hw,c] bf16
__global__ __launch_bounds__(256)
void gn_norm_t(const float* __restrict__ x, const float* __restrict__ mean, const float* __restrict__ rstd,
               const float* __restrict__ gamma, const float* __restrict__ beta,
               unsigned short* __restrict__ xnT) {
    __shared__ unsigned short tile[64][72];
    int i0 = blockIdx.x * 64, c0 = blockIdx.y * 64, b = blockIdx.z;
    float m = mean[b * 8 + blockIdx.y];
    float r = rstd[b * 8 + blockIdx.y];
    int tid = threadIdx.x;
    int tr = tid >> 4, tc = (tid & 15) * 4;
    const float* xb = x + ((size_t)b * CD + c0) * HW + i0;
#pragma unroll
    for (int p = 0; p < 4; ++p) {
        int c = tr + p * 16;
        float g = gamma[c0 + c] * r;
        float bb = beta[c0 + c] - m * g;
        float4 v = *(const float4*)(xb + (size_t)c * HW + tc);
        tile[c][tc + 0] = f2bf(v.x * g + bb);
        tile[c][tc + 1] = f2bf(v.y * g + bb);
        tile[c][tc + 2] = f2bf(v.z * g + bb);
        tile[c][tc + 3] = f2bf(v.w * g + bb);
    }
    __syncthreads();
    unsigned short* ob = xnT + ((size_t)b * HW + i0) * CD + c0;
#pragma unroll
    for (int p = 0; p < 4; ++p) {
        int ir = tr + p * 16;
        ushort4 u;
        u.x = tile[tc + 0][ir];
        u.y = tile[tc + 1][ir];
        u.z = tile[tc + 2][ir];
        u.w = tile[tc + 3][ir];
        *(ushort4*)(ob + (size_t)ir * CD + tc) = u;
    }
}

// ---------------- f32 -> bf16 weight convert (qkv_w rows 0..1023)
__global__ __launch_bounds__(256)
void cvt_bf16(const float* __restrict__ src, unsigned short* __restrict__ dst) {
    int i = blockIdx.x * 256 + threadIdx.x;
    float4 v = ((const float4*)src)[i];
    ushort4 u;
    u.x = f2bf(v.x); u.y = f2bf(v.y); u.z = f2bf(v.z); u.w = f2bf(v.w);
    ((ushort4*)dst)[i] = u;
}

// ---------------- W2 = out_w @ w_v (f32 math, bf16 store); bias2 = out_w @ b_v
__global__ __launch_bounds__(256)
void w2_kernel(const float* __restrict__ out_w, const float* __restrict__ qkv_w,
               const float* __restrict__ qkv_b, unsigned short* __restrict__ w2,
               float* __restrict__ bias2) {
    int bo = blockIdx.x;          // 256 blocks x 2 rows
    int tid = threadIdx.x;        // 256 threads x 2 cols
    int c2 = tid * 2;
    const float* wv = qkv_w + (size_t)1024 * CD;
    const float* bv = qkv_b + 1024;
    float acc0[2] = {}, acc1[2] = {}, b2[2] = {};
    for (int t = 0; t < CD; ++t) {
        float2 v = *(const float2*)(wv + (size_t)t * CD + c2);
        float bvt = bv[t];
#pragma unroll
        for (int r = 0; r < 2; ++r) {
            float ow = out_w[(size_t)(bo * 2 + r) * CD + t];
            acc0[r] += ow * v.x;
            acc1[r] += ow * v.y;
            b2[r]   += ow * bvt;
        }
    }
#pragma unroll
    for (int r = 0; r < 2; ++r) {
        unsigned int pack = (unsigned int)f2bf(acc0[r]) | ((unsigned int)f2bf(acc1[r]) << 16);
        *(unsigned int*)(w2 + (size_t)(bo * 2 + r) * CD + c2) = pack;
        if (tid == 0) bias2[bo * 2 + r] = b2[r];
    }
}

// ---------------- generic bf16 GEMM, C[M,N] = A[M,K] * B[N,K]^T
// EPI 0: bf16 out + bias[col]   (qk^T)
// EPI 1: bf16 out + bias[row]   (vproj)
// EPI 2: f32 out + bias[row] + residual   (final)
template<int EPI>
__global__ __launch_bounds__(256, 2)
void gemm_bt(const unsigned short* __restrict__ A, const unsigned short* __restrict__ B,
             void* __restrict__ Cv, const float* __restrict__ bias,
             const float* __restrict__ resid,
             int M, int N, int K, long long sA, long long sB, long long sC, long long sR) {
    // bijective XCD swizzle (grid always divisible by 8)
    unsigned nx = gridDim.x, ny = gridDim.y;
    unsigned lin = blockIdx.x + nx * (blockIdx.y + ny * blockIdx.z);
    unsigned nwg = nx * ny * gridDim.z;
    unsigned work = (lin & 7) * (nwg >> 3) + (lin >> 3);
    unsigned bx = work % nx; work /= nx;
    unsigned by = work % ny;
    unsigned bz = work / ny;

    A += (size_t)bz * sA;
    B += (size_t)bz * sB;
    int m0 = by * 128, n0 = bx * 128;

    __shared__ unsigned short lA[128 * 64];
    __shared__ unsigned short lB[128 * 64];

    int tid = threadIdx.x;
    int lane = tid & 63;
    int wr = (tid >> 6) >> 1, wc = (tid >> 6) & 1;   // 2x2 waves, 64x64 each

    f32x4 acc[4][4] = {};

    int strow[4], stcol[4];
#pragma unroll
    for (int s = 0; s < 4; ++s) {
        int row = (s * 256 + tid) >> 3;
        int g = (tid & 7) ^ (row & 7);
        strow[s] = row;
        stcol[s] = g * 8;
    }

    for (int k0 = 0; k0 < K; k0 += 64) {
#pragma unroll
        for (int s = 0; s < 4; ++s) {
            GLD16(A + (size_t)(m0 + strow[s]) * K + k0 + stcol[s], lA + (size_t)(s * 256 + tid) * 8);
            GLD16(B + (size_t)(n0 + strow[s]) * K + k0 + stcol[s], lB + (size_t)(s * 256 + tid) * 8);
        }
        __syncthreads();
#pragma unroll
        for (int kk = 0; kk < 64; kk += 32) {
            bf16x8 af[4], bfr[4];
#pragma unroll
            for (int m = 0; m < 4; ++m) {
                int row = wr * 64 + m * 16 + (lane & 15);
                int off = (row * 128 + (kk + (lane >> 4) * 8) * 2) ^ ((row & 7) << 4);
                af[m] = *(const bf16x8*)((const char*)lA + off);
            }
#pragma unroll
            for (int n = 0; n < 4; ++n) {
                int row = wc * 64 + n * 16 + (lane & 15);
                int off = (row * 128 + (kk + (lane >> 4) * 8) * 2) ^ ((row & 7) << 4);
                bfr[n] = *(const bf16x8*)((const char*)lB + off);
            }
#pragma unroll
            for (int m = 0; m < 4; ++m)
#pragma unroll
                for (int n = 0; n < 4; ++n)
                    acc[m][n] = __builtin_amdgcn_mfma_f32_16x16x32_bf16(af[m], bfr[n], acc[m][n], 0, 0, 0);
        }
        __syncthreads();
    }

    int rl = (lane >> 4) * 4;
    int cl = lane & 15;
    if (EPI == 2) {
        float* Cf = (float*)Cv + (size_t)bz * sC;
        const float* Rs = resid + (size_t)bz * sR;
#pragma unroll
        for (int m = 0; m < 4; ++m)
#pragma unroll
            for (int n = 0; n < 4; ++n) {
                int gm = m0 + wr * 64 + m * 16 + rl;
                int gn = n0 + wc * 64 + n * 16 + cl;
#pragma unroll
                for (int rg = 0; rg < 4; ++rg) {
                    size_t off = (size_t)(gm + rg) * N + gn;
                    Cf[off] = acc[m][n][rg] + bias[gm + rg] + Rs[off];
                }
            }
    } else {
        unsigned short* Cb = (unsigned short*)Cv + (size_t)bz * sC;
#pragma unroll
        for (int m = 0; m < 4; ++m)
#pragma unroll
            for (int n = 0; n < 4; ++n) {
                int gm = m0 + wr * 64 + m * 16 + rl;
                int gn = n0 + wc * 64 + n * 16 + cl;
#pragma unroll
                for (int rg = 0; rg < 4; ++rg) {
                    float v = acc[m][n][rg] + (EPI == 0 ? bias[gn] : bias[gm + rg]);
                    Cb[(size_t)(gm + rg) * N + gn] = f2bf(v);
                }
            }
    }
}

// ---------------- scores GEMM: t[b,i,j] = (q_i . k_j) * scale * log2(e), stored bf16
// Also writes per-(row, col-tile) stats: tmax (log2-domain max), tsum (sum exp2(t - tmax)).
// A = qk[b,i,0:512] (q), B = qk[b,j,512:1024] (k). Same tile structure as gemm_bt.
__global__ __launch_bounds__(256, 2)
void scores_gemm(const unsigned short* __restrict__ qk, unsigned short* __restrict__ S,
                 float* __restrict__ tmax, float* __restrict__ tsum) {
    unsigned lin = blockIdx.x + 8u * (blockIdx.y + 8u * blockIdx.z);
    unsigned work = (lin & 7) * 256 + (lin >> 3);   // nwg = 2048
    unsigned bx = work & 7; work >>= 3;             // col tile (jt)
    unsigned by = work & 7;                         // row tile
    unsigned bz = work >> 3;                        // batch
    const unsigned short* qkb = qk + (size_t)bz * HW * HW;
    int m0 = by * 128, n0 = bx * 128;

    __shared__ unsigned short lA[128 * 64];
    __shared__ unsigned short lB[128 * 64];
    __shared__ float redm[2][128];
    __shared__ float reds[2][128];

    int tid = threadIdx.x, lane = tid & 63;
    int wr = (tid >> 6) >> 1, wc = (tid >> 6) & 1;

    f32x4 acc[4][4] = {};
    int strow[4], stcol[4];
#pragma unroll
    for (int s = 0; s < 4; ++s) {
        int row = (s * 256 + tid) >> 3;
        int g = (tid & 7) ^ (row & 7);
        strow[s] = row;
        stcol[s] = g * 8;
    }

    for (int k0 = 0; k0 < CD; k0 += 64) {
#pragma unroll
        for (int s = 0; s < 4; ++s) {
            GLD16(qkb + (size_t)(m0 + strow[s]) * HW + k0 + stcol[s], lA + (size_t)(s * 256 + tid) * 8);
            GLD16(qkb + (size_t)(n0 + strow[s]) * HW + 512 + k0 + stcol[s], lB + (size_t)(s * 256 + tid) * 8);
        }
        __syncthreads();
#pragma unroll
        for (int kk = 0; kk < 64; kk += 32) {
            bf16x8 af[4], bfr[4];
#pragma unroll
            for (int m = 0; m < 4; ++m) {
                int row = wr * 64 + m * 16 + (lane & 15);
                int off = (row * 128 + (kk + (lane >> 4) * 8) * 2) ^ ((row & 7) << 4);
                af[m] = *(const bf16x8*)((const char*)lA + off);
            }
#pragma unroll
            for (int n = 0; n < 4; ++n) {
                int row = wc * 64 + n * 16 + (lane & 15);
                int off = (row * 128 + (kk + (lane >> 4) * 8) * 2) ^ ((row & 7) << 4);
                bfr[n] = *(const bf16x8*)((const char*)lB + off);
            }
#pragma unroll
            for (int m = 0; m < 4; ++m)
#pragma unroll
                for (int n = 0; n < 4; ++n)
                    acc[m][n] = __builtin_amdgcn_mfma_f32_16x16x32_bf16(af[m], bfr[n], acc[m][n], 0, 0, 0);
        }
        __syncthreads();
    }

    const float SL2E = 0.044194173824159216f * 1.4426950408889634f;
#pragma unroll
    for (int m = 0; m < 4; ++m)
#pragma unroll
        for (int n = 0; n < 4; ++n) acc[m][n] *= SL2E;

    int rl = (lane >> 4) * 4;
    int cl = lane & 15;

    // per-row max over this 128-col tile: in-lane (n), shfl (cl group), LDS (wc)
    float mr[4][4];
#pragma unroll
    for (int m = 0; m < 4; ++m)
#pragma unroll
        for (int rg = 0; rg < 4; ++rg)
            mr[m][rg] = fmaxf(fmaxf(acc[m][0][rg], acc[m][1][rg]),
                              fmaxf(acc[m][2][rg], acc[m][3][rg]));
#pragma unroll
    for (int d = 1; d < 16; d <<= 1)
#pragma unroll
        for (int m = 0; m < 4; ++m)
#pragma unroll
            for (int rg = 0; rg < 4; ++rg) mr[m][rg] = fmaxf(mr[m][rg], __shfl_xor(mr[m][rg], d));
    if ((lane & 15) == 0)
#pragma unroll
        for (int m = 0; m < 4; ++m)
#pragma unroll
            for (int rg = 0; rg < 4; ++rg) redm[wc][wr * 64 + m * 16 + rl + rg] = mr[m][rg];
    __syncthreads();
    float Mt[4][4];
#pragma unroll
    for (int m = 0; m < 4; ++m)
#pragma unroll
        for (int rg = 0; rg < 4; ++rg) {
            int row = wr * 64 + m * 16 + rl + rg;
            Mt[m][rg] = fmaxf(redm[0][row], redm[1][row]);
        }

    // per-row sum of exp2(t - Mt)
    float sr[4][4] = {};
#pragma unroll
    for (int m = 0; m < 4; ++m)
#pragma unroll
        for (int n = 0; n < 4; ++n)
#pragma unroll
            for (int rg = 0; rg < 4; ++rg) sr[m][rg] += exp2f(acc[m][n][rg] - Mt[m][rg]);
#pragma unroll
    for (int d = 1; d < 16; d <<= 1)
#pragma unroll
        for (int m = 0; m < 4; ++m)
#pragma unroll
            for (int rg = 0; rg < 4; ++rg) sr[m][rg] += __shfl_xor(sr[m][rg], d);
    if ((lane & 15) == 0)
#pragma unroll
        for (int m = 0; m < 4; ++m)
#pragma unroll
            for (int rg = 0; rg < 4; ++rg) reds[wc][wr * 64 + m * 16 + rl + rg] = sr[m][rg];
    __syncthreads();

    if (tid < 128) {
        float M = fmaxf(redm[0][tid], redm[1][tid]);
        float Z = reds[0][tid] + reds[1][tid];
        size_t o = ((size_t)bz * 8 + bx) * HW + m0 + tid;
        tmax[o] = M;
        tsum[o] = Z;
    }

    // store t (log2-domain scores) bf16
    unsigned short* Sb = S + (size_t)bz * HW * HW;
#pragma unroll
    for (int m = 0; m < 4; ++m)
#pragma unroll
        for (int n = 0; n < 4; ++n) {
            int gm = m0 + wr * 64 + m * 16 + rl;
            int gn = n0 + wc * 64 + n * 16 + cl;
#pragma unroll
            for (int rg = 0; rg < 4; ++rg)
                Sb[(size_t)(gm + rg) * HW + gn] = f2bf(acc[m][n][rg]);
        }
}

// ---------------- combine 8 col-tile stats per row -> rowM, rowRZ
__global__ __launch_bounds__(256)
void row_reduce(const float* __restrict__ tmax, const float* __restrict__ tsum,
                float* __restrict__ rowM, float* __restrict__ rowRZ) {
    int r = blockIdx.x * 256 + threadIdx.x;     // 32*1024 rows
    int b = r >> 10, i = r & 1023;
    const float* tm = tmax + (size_t)b * 8 * HW + i;
    const float* ts = tsum + (size_t)b * 8 * HW + i;
    float M = -1e30f;
#pragma unroll
    for (int jt = 0; jt < 8; ++jt) M = fmaxf(M, tm[(size_t)jt * HW]);
    float Z = 0.f;
#pragma unroll
    for (int jt = 0; jt < 8; ++jt) Z += ts[(size_t)jt * HW] * exp2f(tm[(size_t)jt * HW] - M);
    rowM[r] = M;
    rowRZ[r] = 1.0f / Z;
}

// ---------------- in-place normalize: P = exp2(t - rowM) * rowRZ  (bf16 -> bf16)
__global__ __launch_bounds__(256)
void pnorm(unsigned short* __restrict__ SP, const float* __restrict__ rowM,
           const float* __restrict__ rowRZ) {
    size_t gid = (size_t)blockIdx.x * 256 + threadIdx.x;   // 8 elems/thread, 128 threads/row
    int row = (int)(gid >> 7);
    float M = rowM[row], rz = rowRZ[row];
    uint4 v = ((const uint4*)SP)[gid];
    unsigned* w = (unsigned*)&v;
#pragma unroll
    for (int k = 0; k < 4; ++k) {
        float a = bf2f((unsigned short)(w[k] & 0xffff));
        float c = bf2f((unsigned short)(w[k] >> 16));
        a = exp2f(a - M) * rz;
        c = exp2f(c - M) * rz;
        w[k] = (unsigned)f2bf(a) | ((unsigned)f2bf(c) << 16);
    }
    ((uint4*)SP)[gid] = v;
}

// ---------------- launch
extern "C" void kernel_launch(void* const* d_in, const int* in_sizes, int n_in,
                              void* d_out, int out_size, void* d_ws, size_t ws_size,
                              hipStream_t stream) {
    const float* x      = (const float*)d_in[0];
    const float* gamma  = (const float*)d_in[1];
    const float* beta   = (const float*)d_in[2];
    const float* qkv_w  = (const float*)d_in[3];
    const float* qkv_b  = (const float*)d_in[4];
    const float* out_w  = (const float*)d_in[5];
    const float* out_b  = (const float*)d_in[6];

    char* ws = (char*)d_ws;
    unsigned short* xnT  = (unsigned short*)ws;                   // 32 MB; dead after proj GEMMs
    unsigned short* SP   = (unsigned short*)ws;                   // 64 MB S/P (aliases xnT)
    unsigned short* vpr  = (unsigned short*)(ws + 67108864);      // 32 MB
    unsigned short* wqk  = (unsigned short*)(ws + 100663296);     // 1 MB
    unsigned short* w2   = (unsigned short*)(ws + 101711872);     // 512 KB
    float* bias2         = (float*)(ws + 102236160);
    float* meanp         = (float*)(ws + 102238208);
    float* rstdp         = (float*)(ws + 102239232);
    float* tmaxp         = (float*)(ws + 102760448);              // 1 MB
    float* tsump         = (float*)(ws + 103809024);              // 1 MB
    float* rowMp         = (float*)(ws + 104857600);              // 128 KB
    float* rowRZp        = (float*)(ws + 104988672);              // 128 KB

    unsigned short* qkT = (unsigned short*)d_out;   // 64 MB scratch, overwritten by final GEMM
    float* outF = (float*)d_out;

    gn_stats<<<256, 256, 0, stream>>>(x, meanp, rstdp);
    gn_norm_t<<<dim3(16, 8, 32), 256, 0, stream>>>(x, meanp, rstdp, gamma, beta, xnT);
    cvt_bf16<<<512, 256, 0, stream>>>(qkv_w, wqk);
    w2_kernel<<<256, 256, 0, stream>>>(out_w, qkv_w, qkv_b, w2, bias2);

    // qk^T[b,i,o] = xnT[b,i,:] . qkv_w[o,:]  + qkv_b[o]
    gemm_bt<0><<<dim3(8, 8, 32), 256, 0, stream>>>(xnT, wqk, qkT, qkv_b, nullptr,
        1024, 1024, 512, 1024LL * 512, 0, 1024LL * 1024, 0);
    // vproj[b,o,i] = W2[o,:] . xnT[b,i,:] + bias2[o]
    gemm_bt<1><<<dim3(8, 4, 32), 256, 0, stream>>>(w2, xnT, vpr, bias2, nullptr,
        512, 1024, 512, 0, 1024LL * 512, 512LL * 1024, 0);
    // t = q^T k * scale * log2(e)  (bf16, log2 domain) + per-tile row stats
    scores_gemm<<<dim3(8, 8, 32), 256, 0, stream>>>(qkT, SP, tmaxp, tsump);
    // per-row global max / normalizer
    row_reduce<<<128, 256, 0, stream>>>(tmaxp, tsump, rowMp, rowRZp);
    // P = exp2(t - M) * rZ, in place
    pnorm<<<16384, 256, 0, stream>>>(SP, rowMp, rowRZp);
    // out[b,o,i] = vproj[b,o,:] . P[b,i,:] + out_b[o] + x[b,o,i]
    gemm_bt<2><<<dim3(8, 4, 32), 256, 0, stream>>>(vpr, SP, outF, out_b, x,
        512, 1024, 1024, 512LL * 1024, 1024LL * 1024, 512LL * 1024, 512LL * 1024);
    (void)in_sizes; (void)n_in; (void)out_size; (void)ws_size;
}